// Round 13
// baseline (419.059 us; speedup 1.0000x reference)
//
#include <hip/hip_runtime.h>
#include <hip/hip_bf16.h>

// MicroContinuumCell — MI355X. f32 I/O; bf16 MFMA internally.
// v13 = r12 with k_main at 512 blocks x 512 rows (2 blocks/CU): block-level
// overlap hides barrier drains & staging latency. Structure otherwise
// identical (frag-packed B, frag-ordered XOR LDS, 2 barriers/32-row subtile).
// Workspace (~203 MB): offsets in kernel_launch.

#define NTOK 262144

typedef short s16x4 __attribute__((ext_vector_type(4)));
typedef short s16x8 __attribute__((ext_vector_type(8)));
typedef float f32x4 __attribute__((ext_vector_type(4)));
typedef unsigned int u32x4 __attribute__((ext_vector_type(4)));
typedef __bf16 bf16x8 __attribute__((ext_vector_type(8)));

static __device__ __forceinline__ float b2f(short s) {
  unsigned int u = ((unsigned int)(unsigned short)s) << 16;
  return __builtin_bit_cast(float, u);
}
static __device__ __forceinline__ short f2b(float f) {
  __hip_bfloat16 h = __float2bfloat16(f);
  return (short)__builtin_bit_cast(unsigned short, h);
}
static __device__ __forceinline__ float clip2(float f) {
  return fminf(2.f, fmaxf(-2.f, f));
}
static __device__ __forceinline__ unsigned int packu(short lo, short hi) {
  return (unsigned int)(unsigned short)lo | ((unsigned int)(unsigned short)hi << 16);
}
static __device__ __forceinline__ f32x4 mfma16(s16x8 a, s16x8 b, f32x4 c) {
  return __builtin_amdgcn_mfma_f32_16x16x32_bf16(
      __builtin_bit_cast(bf16x8, a), __builtin_bit_cast(bf16x8, b), c, 0, 0, 0);
}

// ---------------------------------------------------------------- k_prep
// Fragment-packs V,W into Vf,Wf (wave B-frag load = 1KB contiguous) + |W|^2.
__global__ __launch_bounds__(1024) void k_prep(const float* __restrict__ V,
                                               const float* __restrict__ W,
                                               short* __restrict__ Vf,
                                               short* __restrict__ Wf,
                                               float* __restrict__ scal) {
  int t = blockIdx.x * 1024 + threadIdx.x;  // 16384 threads x 4 elems
  int flat = t * 4;
  int col = flat >> 8, k0 = flat & 255;
  f32x4 v4 = *(const f32x4*)(V + flat);
  f32x4 w4 = *(const f32x4*)(W + flat);
  s16x4 vb, wb;
  float s = 0.f;
#pragma unroll
  for (int e = 0; e < 4; ++e) {
    vb[e] = f2b(v4[e]);
    wb[e] = f2b(w4[e]);
    s += w4[e] * w4[e];
  }
  int cb = col >> 4, lrr = col & 15;
  int ks = k0 >> 5, lgg = (k0 >> 3) & 3, j0 = k0 & 7;
  size_t g = (size_t)(((cb * 8 + ks) * 4 + lgg) * 16 + lrr) * 8 + j0;
  *(s16x4*)(Vf + g) = vb;
  *(s16x4*)(Wf + g) = wb;
#pragma unroll
  for (int d = 1; d < 64; d <<= 1) s += __shfl_xor(s, d);
  __shared__ float r[16];
  if ((threadIdx.x & 63) == 0) r[threadIdx.x >> 6] = s;
  __syncthreads();
  if (threadIdx.x == 0) {
    float tt = 0.f;
#pragma unroll
    for (int i = 0; i < 16; ++i) tt += r[i];
    atomicAdd(&scal[0], tt);
  }
}

// ---------------------------------------------------------------- k_main
// 512 blocks x 512 threads; 512 rows/block; 16 subtiles of 32 rows.
// 2 blocks/CU (VGPR 112, LDS ~40.6KB) so barrier drains overlap across
// blocks. Per subtile: [copy prev v out] + stage x -> barrier ->
// 64 MFMA/wave + partials + vs bounce -> barrier. Block end: MLP.
__global__ __launch_bounds__(512) void k_main(
    const float* __restrict__ x, const short* __restrict__ Vf,
    const short* __restrict__ Wf, const float* __restrict__ gw,
    const float* __restrict__ gb, const float* __restrict__ s1w,
    const float* __restrict__ s1b, const float* __restrict__ lng,
    const float* __restrict__ lnb, const float* __restrict__ s2w,
    const float* __restrict__ s2b, const float* __restrict__ aw,
    const float* __restrict__ ab, short* __restrict__ v_out,
    float* __restrict__ g_out, float* __restrict__ scal) {
  __shared__ __align__(16) short xs[1024 * 8];   // 16 KiB, frag-ordered
  __shared__ __align__(16) short vs[32 * 264];   // 16.5 KiB v bounce
  __shared__ float stat[2048];  // [0)gate [512)|h| [1024)sx [1536)sxx
  int tid = threadIdx.x;
  int lane = tid & 63, wid = tid >> 6;
  int lr = lane & 15, lg = lane >> 4;
  int np = tid >> 5, ic = tid & 31;  // staging: rows 2np,2np+1; cols ic*8
  int c0 = wid * 32;                 // wave's 32-col slice (both products)
  size_t n0 = (size_t)blockIdx.x * 512;

#pragma unroll
  for (int q = 0; q < 4; ++q) stat[q * 512 + tid] = 0.f;

  float gw0 = gw[c0 + lr], gw1 = gw[c0 + 16 + lr];
  int sks = ic >> 2, slg = ic & 3;  // staging granule coords

  for (int nt = 0; nt < 16; ++nt) {
    int rbase = nt * 32;
    // ---- copy previous subtile's v out (overlaps staging loads)
    if (nt > 0) {
#pragma unroll
      for (int q = 0; q < 2; ++q) {
        int item = q * 512 + tid;
        int row = item >> 5, c8 = item & 31;
        *(s16x8*)(v_out + (n0 + rbase - 32 + row) * 256 + c8 * 8) =
            *(const s16x8*)(vs + row * 264 + c8 * 8);
      }
    }
    // ---- stage x: rows 2np,2np+1, cols ic*8..+7 -> frag-ordered slots
    {
      const float* pa = x + (n0 + rbase + 2 * np) * 256 + ic * 8;
      f32x4 xa0 = *(const f32x4*)pa;
      f32x4 xa1 = *(const f32x4*)(pa + 4);
      f32x4 xb0 = *(const f32x4*)(pa + 256);
      f32x4 xb1 = *(const f32x4*)(pa + 260);
      s16x8 ca, cb;
      float sA = 0.f, qA = 0.f, sB = 0.f, qB = 0.f;
#pragma unroll
      for (int j = 0; j < 4; ++j) {
        sA += xa0[j] + xa1[j];
        qA += xa0[j] * xa0[j] + xa1[j] * xa1[j];
        sB += xb0[j] + xb1[j];
        qB += xb0[j] * xb0[j] + xb1[j] * xb1[j];
        ca[j] = f2b(xa0[j]); ca[4 + j] = f2b(xa1[j]);
        cb[j] = f2b(xb0[j]); cb[4 + j] = f2b(xb1[j]);
      }
      int rowa = 2 * np, rowb = 2 * np + 1;
      int sa = ((rowa >> 4) * 8 + sks) * 64 + ((slg * 16 + (rowa & 15)) ^ sks);
      int sb = ((rowb >> 4) * 8 + sks) * 64 + ((slg * 16 + (rowb & 15)) ^ sks);
      *(s16x8*)(xs + sa * 8) = ca;
      *(s16x8*)(xs + sb * 8) = cb;
#pragma unroll
      for (int d = 1; d < 32; d <<= 1) {
        sA += __shfl_xor(sA, d); qA += __shfl_xor(qA, d);
        sB += __shfl_xor(sB, d); qB += __shfl_xor(qB, d);
      }
      if (ic == 0) {
        stat[1024 + rbase + 2 * np] = sA;
        stat[1536 + rbase + 2 * np] = qA;
        stat[1024 + rbase + 2 * np + 1] = sB;
        stat[1536 + rbase + 2 * np + 1] = qB;
      }
    }
    __syncthreads();
    // ---- compute: 64 MFMAs, no barrier inside
    f32x4 av[2][2] = {}, ah[2][2] = {};
#pragma unroll
    for (int ks = 0; ks < 8; ++ks) {
      s16x8 a0 = *(const s16x8*)(xs + ((ks * 64) + (lane ^ ks)) * 8);
      s16x8 a1 = *(const s16x8*)(xs + (((8 + ks) * 64) + (lane ^ ks)) * 8);
      s16x8 bv0 = *(const s16x8*)(Vf + (size_t)(((wid * 2 + 0) * 8 + ks) * 64 + lane) * 8);
      s16x8 bv1 = *(const s16x8*)(Vf + (size_t)(((wid * 2 + 1) * 8 + ks) * 64 + lane) * 8);
      s16x8 bw0 = *(const s16x8*)(Wf + (size_t)(((wid * 2 + 0) * 8 + ks) * 64 + lane) * 8);
      s16x8 bw1 = *(const s16x8*)(Wf + (size_t)(((wid * 2 + 1) * 8 + ks) * 64 + lane) * 8);
      av[0][0] = mfma16(a0, bv0, av[0][0]);
      av[0][1] = mfma16(a0, bv1, av[0][1]);
      av[1][0] = mfma16(a1, bv0, av[1][0]);
      av[1][1] = mfma16(a1, bv1, av[1][1]);
      ah[0][0] = mfma16(a0, bw0, ah[0][0]);
      ah[0][1] = mfma16(a0, bw1, ah[0][1]);
      ah[1][0] = mfma16(a1, bw0, ah[1][0]);
      ah[1][1] = mfma16(a1, bw1, ah[1][1]);
    }
    // clip v, gate-dot & |h| row-partials, v -> vs bounce
#pragma unroll
    for (int mf = 0; mf < 2; ++mf)
#pragma unroll
      for (int e = 0; e < 4; ++e) {
        float v0 = clip2(av[mf][0][e]), v1 = clip2(av[mf][1][e]);
        av[mf][0][e] = v0; av[mf][1][e] = v1;
        float gd = v0 * gw0 + v1 * gw1;
        float hs = fabsf(ah[mf][0][e]) + fabsf(ah[mf][1][e]);
#pragma unroll
        for (int d = 1; d < 16; d <<= 1) {
          gd += __shfl_xor(gd, d);
          hs += __shfl_xor(hs, d);
        }
        if (lr == 0) {
          int row = rbase + mf * 16 + lg * 4 + e;
          atomicAdd(&stat[row], gd);
          atomicAdd(&stat[512 + row], hs);
        }
      }
#pragma unroll
    for (int mf = 0; mf < 2; ++mf)
#pragma unroll
      for (int nf = 0; nf < 2; ++nf)
#pragma unroll
        for (int e = 0; e < 4; ++e)
          vs[(mf * 16 + lg * 4 + e) * 264 + c0 + nf * 16 + lr] =
              f2b(av[mf][nf][e]);
    __syncthreads();
  }
  // final subtile's v copy-out
#pragma unroll
  for (int q = 0; q < 2; ++q) {
    int item = q * 512 + tid;
    int row = item >> 5, c8 = item & 31;
    *(s16x8*)(v_out + (n0 + 480 + row) * 256 + c8 * 8) =
        *(const s16x8*)(vs + row * 264 + c8 * 8);
  }

  // ---- deferred per-row MLP: 1 row/thread
  float c0s = 0.f, c2s = 0.f;
  float wnorm = sqrtf(scal[0]);
  {
    int r = tid;
    float mean = stat[1024 + r] * (1.f / 256.f);
    float var = stat[1536 + r] * (1.f / 256.f) - mean * mean;
    float st[4];
    st[0] = fabsf(var - 0.5f);
    st[1] = stat[512 + r] * (1.f / 256.f);
    st[2] = wnorm;
    st[3] = 0.5f;
    float z[16];
#pragma unroll
    for (int o = 0; o < 16; ++o) {
      float a = s1b[o];
#pragma unroll
      for (int i = 0; i < 4; ++i) a += s1w[o * 4 + i] * st[i];
      z[o] = a;
    }
    float mu = 0.f;
#pragma unroll
    for (int o = 0; o < 16; ++o) mu += z[o];
    mu *= (1.f / 16.f);
    float vz = 0.f;
#pragma unroll
    for (int o = 0; o < 16; ++o) { float d2 = z[o] - mu; vz += d2 * d2; }
    vz *= (1.f / 16.f);
    float rs = rsqrtf(vz + 1e-5f);
#pragma unroll
    for (int o = 0; o < 16; ++o)
      z[o] = tanhf((z[o] - mu) * rs * lng[o] + lnb[o]);
    float z2[8];
#pragma unroll
    for (int o = 0; o < 8; ++o) {
      float a = s2b[o];
#pragma unroll
      for (int i = 0; i < 16; ++i) a += s2w[o * 16 + i] * z[i];
      z2[o] = fmaxf(a, 0.f);
    }
#pragma unroll
    for (int q = 0; q < 2; ++q) {
      int o = q * 2;  // controls[0], controls[2]
      float a = ab[o];
#pragma unroll
      for (int i = 0; i < 8; ++i) a += aw[o * 8 + i] * z2[i];
      float cc = 1.f / (1.f + expf(-a));
      if (q == 0) c0s += cc; else c2s += cc;
    }
    g_out[n0 + r] = 1.f / (1.f + expf(-(stat[r] + gb[0])));
  }
#pragma unroll
  for (int d = 1; d < 64; d <<= 1) {
    c0s += __shfl_xor(c0s, d);
    c2s += __shfl_xor(c2s, d);
  }
  if (lane == 0) {
    atomicAdd(&scal[1], c0s);
    atomicAdd(&scal[2], c2s);
  }
}

// ---------------------------------------------------------------- k_hebb
// At its traffic roofline (~110us for ~737MB) — unchanged from r11/r12.
__global__ __launch_bounds__(512, 2) void k_hebb(
    const float* __restrict__ x, const short* __restrict__ v_in,
    const float* __restrict__ g_sig, const float* __restrict__ scal,
    float* __restrict__ colv2, float* __restrict__ parts,
    float* __restrict__ out0) {
  __shared__ __align__(16) unsigned int ldsT[2 * 256 * 17];  // 34 KiB
  unsigned int* vT = ldsT;
  unsigned int* xT = ldsT + 256 * 17;
  int tid = threadIdx.x;
  int lane = tid & 63, wid = tid >> 6;
  int lr = lane & 15, lg = lane >> 4;
  int wr = wid >> 2, wc = wid & 3;
  size_t n0 = (size_t)blockIdx.x * 1024;
  float gv = scal[2] * (1.f / 262144.f);  // gate_value

  f32x4 acc[8][4] = {};
  float cv2[8] = {0.f, 0.f, 0.f, 0.f, 0.f, 0.f, 0.f, 0.f};
  int np = tid >> 5, ic = tid & 31, i0 = ic * 8;

  for (int nt = 0; nt < 32; ++nt) {
    size_t nr = n0 + nt * 32 + np * 2;
    s16x8 va = *(const s16x8*)(v_in + nr * 256 + i0);
    s16x8 vb = *(const s16x8*)(v_in + (nr + 1) * 256 + i0);
    f32x4 xa0 = *(const f32x4*)(x + nr * 256 + i0);
    f32x4 xa1 = *(const f32x4*)(x + nr * 256 + i0 + 4);
    f32x4 xb0 = *(const f32x4*)(x + (nr + 1) * 256 + i0);
    f32x4 xb1 = *(const f32x4*)(x + (nr + 1) * 256 + i0 + 4);
    float sa = g_sig[nr] * gv, sb = g_sig[nr + 1] * gv;
    f32x4 oa0, oa1, ob0, ob1;
#pragma unroll
    for (int j = 0; j < 4; ++j) {
      float fa = b2f(va[j]), fA = b2f(va[4 + j]);
      float fb = b2f(vb[j]), fB = b2f(vb[4 + j]);
      cv2[j] += fa * fa + fb * fb;
      cv2[4 + j] += fA * fA + fB * fB;
      oa0[j] = clip2(fa * sa); oa1[j] = clip2(fA * sa);
      ob0[j] = clip2(fb * sb); ob1[j] = clip2(fB * sb);
      vT[(i0 + j) * 17 + np] = packu(va[j], vb[j]);
      vT[(i0 + 4 + j) * 17 + np] = packu(va[4 + j], vb[4 + j]);
      xT[(i0 + j) * 17 + np] = packu(f2b(xa0[j]), f2b(xb0[j]));
      xT[(i0 + 4 + j) * 17 + np] = packu(f2b(xa1[j]), f2b(xb1[j]));
    }
    *(f32x4*)(out0 + nr * 256 + i0) = oa0;
    *(f32x4*)(out0 + nr * 256 + i0 + 4) = oa1;
    *(f32x4*)(out0 + (nr + 1) * 256 + i0) = ob0;
    *(f32x4*)(out0 + (nr + 1) * 256 + i0 + 4) = ob1;
    __syncthreads();
    int npb = lg * 4;
    s16x8 bfr[4];
#pragma unroll
    for (int nf = 0; nf < 4; ++nf) {
      int j = wc * 64 + nf * 16 + lr;
      u32x4 q;
      q[0] = xT[j * 17 + npb]; q[1] = xT[j * 17 + npb + 1];
      q[2] = xT[j * 17 + npb + 2]; q[3] = xT[j * 17 + npb + 3];
      bfr[nf] = __builtin_bit_cast(s16x8, q);
    }
#pragma unroll
    for (int mf = 0; mf < 8; ++mf) {
      int i = wr * 128 + mf * 16 + lr;
      u32x4 q;
      q[0] = vT[i * 17 + npb]; q[1] = vT[i * 17 + npb + 1];
      q[2] = vT[i * 17 + npb + 2]; q[3] = vT[i * 17 + npb + 3];
      s16x8 afr = __builtin_bit_cast(s16x8, q);
#pragma unroll
      for (int nf = 0; nf < 4; ++nf)
        acc[mf][nf] = mfma16(afr, bfr[nf], acc[mf][nf]);
    }
    __syncthreads();
  }
  // fragment-ordered parts: each thread's f32x4 contiguous (coalesced 16B)
  float* myp = parts + (size_t)blockIdx.x * 65536;
#pragma unroll
  for (int mf = 0; mf < 8; ++mf)
#pragma unroll
    for (int nf = 0; nf < 4; ++nf)
      *(f32x4*)(myp + (size_t)(((wid * 8 + mf) * 4 + nf) * 64 + lane) * 4) =
          acc[mf][nf];
  __syncthreads();
  float* cred = (float*)ldsT;
  if (tid < 256) cred[tid] = 0.f;
  __syncthreads();
#pragma unroll
  for (int j = 0; j < 8; ++j) atomicAdd(&cred[i0 + j], cv2[j]);
  __syncthreads();
  if (tid < 256) atomicAdd(&colv2[tid], cred[tid]);
}

// ---------------------------------------------------------------- k_mem1
__global__ __launch_bounds__(256) void k_mem1(
    const float* __restrict__ parts, const float* __restrict__ colv2,
    const float* __restrict__ sm, float* __restrict__ mem,
    float* __restrict__ scal) {
  int q = blockIdx.x * 256 + threadIdx.x;  // 0..16383
  const float* src = parts + (size_t)q * 4;
  f32x4 acc = {0.f, 0.f, 0.f, 0.f};
#pragma unroll 4
  for (int p = 0; p < 256; ++p) acc += *(const f32x4*)(src + (size_t)p * 65536);
  int lane2 = q & 63, r = q >> 6;
  int lg = lane2 >> 4, lr = lane2 & 15;
  int nf = r & 3, mf = (r >> 2) & 7, wid = r >> 5;
  int wr = wid >> 2, wc = wid & 3;
  int j = wc * 64 + nf * 16 + lr;
  float mr = scal[1] * (1.f / 262144.f);  // metabolic_rate
  float s = 0.f;
#pragma unroll
  for (int e = 0; e < 4; ++e) {
    int i = wr * 128 + mf * 16 + lg * 4 + e;
    float hebb = acc[e] * (1.f / 262144.f);
    float smv = sm[i * 256 + j];
    float forget = colv2[i] * (1.f / 262144.f) * smv;
    float m = smv + tanhf(hebb - forget) * mr * 0.1f;
    mem[i * 256 + j] = m;
    s += m * m;
  }
#pragma unroll
  for (int d = 1; d < 64; d <<= 1) s += __shfl_xor(s, d);
  __shared__ float r4[4];
  if ((threadIdx.x & 63) == 0) r4[threadIdx.x >> 6] = s;
  __syncthreads();
  if (threadIdx.x == 0) atomicAdd(&scal[3], r4[0] + r4[1] + r4[2] + r4[3]);
}

__global__ __launch_bounds__(256) void k_mem2(const float* __restrict__ mem,
                                              const float* __restrict__ scal,
                                              float* __restrict__ out1) {
  int idx = blockIdx.x * 256 + threadIdx.x;
  float scale = 0.5f / fmaxf(sqrtf(scal[3]), 1e-6f);
  out1[idx] = mem[idx] * scale;
}

// ---------------------------------------------------------------- launch
extern "C" void kernel_launch(void* const* d_in, const int* in_sizes, int n_in,
                              void* d_out, int out_size, void* d_ws, size_t ws_size,
                              hipStream_t stream) {
  (void)in_sizes; (void)n_in; (void)out_size; (void)ws_size;
  const float* x   = (const float*)d_in[0];
  const float* Wm  = (const float*)d_in[1];
  const float* Vm  = (const float*)d_in[2];
  const float* gw  = (const float*)d_in[3];
  const float* gb  = (const float*)d_in[4];
  const float* s1w = (const float*)d_in[5];
  const float* s1b = (const float*)d_in[6];
  const float* lng = (const float*)d_in[7];
  const float* lnb = (const float*)d_in[8];
  const float* s2w = (const float*)d_in[9];
  const float* s2b = (const float*)d_in[10];
  const float* aw  = (const float*)d_in[11];
  const float* ab  = (const float*)d_in[12];
  const float* sm  = (const float*)d_in[13];
  float* out0 = (float*)d_out;
  float* out1 = out0 + (size_t)NTOK * 256;

  char* w = (char*)d_ws;
  short* v_ws  = (short*)w;                    // 134217728
  float* g_ws  = (float*)(w + 134217728);      // 1048576
  float* scal  = (float*)(w + 135266304);      // 256
  float* colv2 = (float*)(w + 135266560);      // 1024
  float* mem   = (float*)(w + 135267584);      // 262144
  float* parts = (float*)(w + 135529728);      // 67108864
  short* Vf    = (short*)(w + 202638592);      // 131072 (frag-packed)
  short* Wf    = (short*)(w + 202769664);      // 131072 (frag-packed)

  hipMemsetAsync(scal, 0, 1280, stream);       // scal[64] + colv2[256]
  k_prep<<<16, 1024, 0, stream>>>(Vm, Wm, Vf, Wf, scal);
  k_main<<<512, 512, 0, stream>>>(x, Vf, Wf, gw, gb, s1w, s1b, lng, lnb,
                                  s2w, s2b, aw, ab, v_ws, g_ws, scal);
  k_hebb<<<256, 512, 0, stream>>>(x, v_ws, g_ws, scal, colv2, parts, out0);
  k_mem1<<<64, 256, 0, stream>>>(parts, colv2, sm, mem, scal);
  k_mem2<<<256, 256, 0, stream>>>(mem, scal, out1);
}

// Round 14
// 370.711 us; speedup vs baseline: 1.1304x; 1.1304x over previous
//
#include <hip/hip_runtime.h>
#include <hip/hip_bf16.h>

// MicroContinuumCell — MI355X. f32 I/O; bf16 MFMA internally.
// v14 = r12 (best: 256 blk x 1024 rows, frag-packed B, frag-ordered XOR LDS)
// + single-barrier pipelined subtile loop: xs/vs double-buffered; x loads for
// nt+1 issued before compute(nt); convert after MFMAs -> staging latency
// hidden; one drain per subtile instead of two.
// Workspace (~203 MB): offsets in kernel_launch.

#define NTOK 262144

typedef short s16x4 __attribute__((ext_vector_type(4)));
typedef short s16x8 __attribute__((ext_vector_type(8)));
typedef float f32x4 __attribute__((ext_vector_type(4)));
typedef unsigned int u32x4 __attribute__((ext_vector_type(4)));
typedef __bf16 bf16x8 __attribute__((ext_vector_type(8)));

static __device__ __forceinline__ float b2f(short s) {
  unsigned int u = ((unsigned int)(unsigned short)s) << 16;
  return __builtin_bit_cast(float, u);
}
static __device__ __forceinline__ short f2b(float f) {
  __hip_bfloat16 h = __float2bfloat16(f);
  return (short)__builtin_bit_cast(unsigned short, h);
}
static __device__ __forceinline__ float clip2(float f) {
  return fminf(2.f, fmaxf(-2.f, f));
}
static __device__ __forceinline__ unsigned int packu(short lo, short hi) {
  return (unsigned int)(unsigned short)lo | ((unsigned int)(unsigned short)hi << 16);
}
static __device__ __forceinline__ f32x4 mfma16(s16x8 a, s16x8 b, f32x4 c) {
  return __builtin_amdgcn_mfma_f32_16x16x32_bf16(
      __builtin_bit_cast(bf16x8, a), __builtin_bit_cast(bf16x8, b), c, 0, 0, 0);
}

// ---------------------------------------------------------------- k_prep
// Fragment-packs V,W into Vf,Wf (wave B-frag load = 1KB contiguous) + |W|^2.
__global__ __launch_bounds__(1024) void k_prep(const float* __restrict__ V,
                                               const float* __restrict__ W,
                                               short* __restrict__ Vf,
                                               short* __restrict__ Wf,
                                               float* __restrict__ scal) {
  int t = blockIdx.x * 1024 + threadIdx.x;  // 16384 threads x 4 elems
  int flat = t * 4;
  int col = flat >> 8, k0 = flat & 255;
  f32x4 v4 = *(const f32x4*)(V + flat);
  f32x4 w4 = *(const f32x4*)(W + flat);
  s16x4 vb, wb;
  float s = 0.f;
#pragma unroll
  for (int e = 0; e < 4; ++e) {
    vb[e] = f2b(v4[e]);
    wb[e] = f2b(w4[e]);
    s += w4[e] * w4[e];
  }
  int cb = col >> 4, lrr = col & 15;
  int ks = k0 >> 5, lgg = (k0 >> 3) & 3, j0 = k0 & 7;
  size_t g = (size_t)(((cb * 8 + ks) * 4 + lgg) * 16 + lrr) * 8 + j0;
  *(s16x4*)(Vf + g) = vb;
  *(s16x4*)(Wf + g) = wb;
#pragma unroll
  for (int d = 1; d < 64; d <<= 1) s += __shfl_xor(s, d);
  __shared__ float r[16];
  if ((threadIdx.x & 63) == 0) r[threadIdx.x >> 6] = s;
  __syncthreads();
  if (threadIdx.x == 0) {
    float tt = 0.f;
#pragma unroll
    for (int i = 0; i < 16; ++i) tt += r[i];
    atomicAdd(&scal[0], tt);
  }
}

// ---------------------------------------------------------------- k_main
// 256 blocks x 512 threads; 1024 rows/block; 32 subtiles of 32 rows.
// Single-barrier pipelined loop (xs/vs double-buffered):
//   copy vs[prev] -> v_out | issue x(nt+1) loads | 64 MFMA from xs[cur]
//   + clip/partials + vs[cur] | convert x regs -> xs[next] | barrier.
__global__ __launch_bounds__(512) void k_main(
    const float* __restrict__ x, const short* __restrict__ Vf,
    const short* __restrict__ Wf, const float* __restrict__ gw,
    const float* __restrict__ gb, const float* __restrict__ s1w,
    const float* __restrict__ s1b, const float* __restrict__ lng,
    const float* __restrict__ lnb, const float* __restrict__ s2w,
    const float* __restrict__ s2b, const float* __restrict__ aw,
    const float* __restrict__ ab, short* __restrict__ v_out,
    float* __restrict__ g_out, float* __restrict__ scal) {
  __shared__ __align__(16) short xs[2][8192];      // 2 x 16 KiB frag-ordered
  __shared__ __align__(16) short vs[2][32 * 264];  // 2 x 16.5 KiB v bounce
  __shared__ float stat[4096];  // [0)gate [1024)|h| [2048)sx [3072)sxx
  int tid = threadIdx.x;
  int lane = tid & 63, wid = tid >> 6;
  int lr = lane & 15, lg = lane >> 4;
  int np = tid >> 5, ic = tid & 31;  // staging: rows 2np,2np+1; cols ic*8
  int c0 = wid * 32;                 // wave's 32-col slice (both products)
  size_t n0 = (size_t)blockIdx.x * 1024;

#pragma unroll
  for (int q = 0; q < 4; ++q) stat[q * 512 + tid] = 0.f;

  float gw0 = gw[c0 + lr], gw1 = gw[c0 + 16 + lr];
  int sks = ic >> 2, slg = ic & 3;
  int rowa = 2 * np, rowb = 2 * np + 1;
  int sa = ((rowa >> 4) * 8 + sks) * 64 + ((slg * 16 + (rowa & 15)) ^ sks);
  int sb = ((rowb >> 4) * 8 + sks) * 64 + ((slg * 16 + (rowb & 15)) ^ sks);

  f32x4 rxa0, rxa1, rxb0, rxb1;  // staged x registers

#define XLOAD(RB)                                              \
  {                                                            \
    const float* pa = x + (n0 + (RB) + rowa) * 256 + ic * 8;   \
    rxa0 = *(const f32x4*)pa;                                  \
    rxa1 = *(const f32x4*)(pa + 4);                            \
    rxb0 = *(const f32x4*)(pa + 256);                          \
    rxb1 = *(const f32x4*)(pa + 260);                          \
  }
#define CONV_STORE(BUF, RB)                                    \
  {                                                            \
    s16x8 ca, cb;                                              \
    float sA = 0.f, qA = 0.f, sB = 0.f, qB = 0.f;              \
    _Pragma("unroll") for (int j = 0; j < 4; ++j) {            \
      sA += rxa0[j] + rxa1[j];                                 \
      qA += rxa0[j] * rxa0[j] + rxa1[j] * rxa1[j];             \
      sB += rxb0[j] + rxb1[j];                                 \
      qB += rxb0[j] * rxb0[j] + rxb1[j] * rxb1[j];             \
      ca[j] = f2b(rxa0[j]); ca[4 + j] = f2b(rxa1[j]);          \
      cb[j] = f2b(rxb0[j]); cb[4 + j] = f2b(rxb1[j]);          \
    }                                                          \
    *(s16x8*)(xs[BUF] + sa * 8) = ca;                          \
    *(s16x8*)(xs[BUF] + sb * 8) = cb;                          \
    _Pragma("unroll") for (int d = 1; d < 32; d <<= 1) {       \
      sA += __shfl_xor(sA, d); qA += __shfl_xor(qA, d);        \
      sB += __shfl_xor(sB, d); qB += __shfl_xor(qB, d);        \
    }                                                          \
    if (ic == 0) {                                             \
      stat[2048 + (RB) + rowa] = sA;                           \
      stat[3072 + (RB) + rowa] = qA;                           \
      stat[2048 + (RB) + rowb] = sB;                           \
      stat[3072 + (RB) + rowb] = qB;                           \
    }                                                          \
  }

  // prologue: stage subtile 0
  XLOAD(0);
  CONV_STORE(0, 0);
  __syncthreads();

  for (int nt = 0; nt < 32; ++nt) {
    int buf = nt & 1;
    int rbase = nt * 32;
    // ---- copy previous subtile's v out (from vs[buf^1])
    if (nt > 0) {
      const short* vsp = vs[buf ^ 1];
#pragma unroll
      for (int q = 0; q < 2; ++q) {
        int item = q * 512 + tid;
        int row = item >> 5, c8 = item & 31;
        *(s16x8*)(v_out + (n0 + rbase - 32 + row) * 256 + c8 * 8) =
            *(const s16x8*)(vsp + row * 264 + c8 * 8);
      }
    }
    // ---- issue next subtile's x loads (consumed AFTER the MFMAs)
    if (nt < 31) XLOAD(rbase + 32);
    // ---- compute: 64 MFMAs from xs[buf], no barrier inside
    f32x4 av[2][2] = {}, ah[2][2] = {};
    const short* xb = xs[buf];
#pragma unroll
    for (int ks = 0; ks < 8; ++ks) {
      s16x8 a0 = *(const s16x8*)(xb + ((ks * 64) + (lane ^ ks)) * 8);
      s16x8 a1 = *(const s16x8*)(xb + (((8 + ks) * 64) + (lane ^ ks)) * 8);
      s16x8 bv0 = *(const s16x8*)(Vf + (size_t)(((wid * 2 + 0) * 8 + ks) * 64 + lane) * 8);
      s16x8 bv1 = *(const s16x8*)(Vf + (size_t)(((wid * 2 + 1) * 8 + ks) * 64 + lane) * 8);
      s16x8 bw0 = *(const s16x8*)(Wf + (size_t)(((wid * 2 + 0) * 8 + ks) * 64 + lane) * 8);
      s16x8 bw1 = *(const s16x8*)(Wf + (size_t)(((wid * 2 + 1) * 8 + ks) * 64 + lane) * 8);
      av[0][0] = mfma16(a0, bv0, av[0][0]);
      av[0][1] = mfma16(a0, bv1, av[0][1]);
      av[1][0] = mfma16(a1, bv0, av[1][0]);
      av[1][1] = mfma16(a1, bv1, av[1][1]);
      ah[0][0] = mfma16(a0, bw0, ah[0][0]);
      ah[0][1] = mfma16(a0, bw1, ah[0][1]);
      ah[1][0] = mfma16(a1, bw0, ah[1][0]);
      ah[1][1] = mfma16(a1, bw1, ah[1][1]);
    }
    // clip v, gate-dot & |h| row-partials, v -> vs[buf]
#pragma unroll
    for (int mf = 0; mf < 2; ++mf)
#pragma unroll
      for (int e = 0; e < 4; ++e) {
        float v0 = clip2(av[mf][0][e]), v1 = clip2(av[mf][1][e]);
        av[mf][0][e] = v0; av[mf][1][e] = v1;
        float gd = v0 * gw0 + v1 * gw1;
        float hs = fabsf(ah[mf][0][e]) + fabsf(ah[mf][1][e]);
#pragma unroll
        for (int d = 1; d < 16; d <<= 1) {
          gd += __shfl_xor(gd, d);
          hs += __shfl_xor(hs, d);
        }
        if (lr == 0) {
          int row = rbase + mf * 16 + lg * 4 + e;
          atomicAdd(&stat[row], gd);
          atomicAdd(&stat[1024 + row], hs);
        }
      }
    {
      short* vsc = vs[buf];
#pragma unroll
      for (int mf = 0; mf < 2; ++mf)
#pragma unroll
        for (int nf = 0; nf < 2; ++nf)
#pragma unroll
          for (int e = 0; e < 4; ++e)
            vsc[(mf * 16 + lg * 4 + e) * 264 + c0 + nf * 16 + lr] =
                f2b(av[mf][nf][e]);
    }
    // ---- convert prefetched x -> xs[buf^1] (loads are ~3000cy old now)
    if (nt < 31) CONV_STORE(buf ^ 1, rbase + 32);
    __syncthreads();
  }
  // final subtile's v copy-out (vs[31&1] = vs[1])
  {
    const short* vsp = vs[1];
#pragma unroll
    for (int q = 0; q < 2; ++q) {
      int item = q * 512 + tid;
      int row = item >> 5, c8 = item & 31;
      *(s16x8*)(v_out + (n0 + 992 + row) * 256 + c8 * 8) =
          *(const s16x8*)(vsp + row * 264 + c8 * 8);
    }
  }
#undef CONV_STORE
#undef XLOAD

  // ---- deferred per-row MLP: 2 rows/thread
  float c0s = 0.f, c2s = 0.f;
  float wnorm = sqrtf(scal[0]);
#pragma unroll
  for (int rr = 0; rr < 2; ++rr) {
    int r = tid + rr * 512;
    float mean = stat[2048 + r] * (1.f / 256.f);
    float var = stat[3072 + r] * (1.f / 256.f) - mean * mean;
    float st[4];
    st[0] = fabsf(var - 0.5f);
    st[1] = stat[1024 + r] * (1.f / 256.f);
    st[2] = wnorm;
    st[3] = 0.5f;
    float z[16];
#pragma unroll
    for (int o = 0; o < 16; ++o) {
      float a = s1b[o];
#pragma unroll
      for (int i = 0; i < 4; ++i) a += s1w[o * 4 + i] * st[i];
      z[o] = a;
    }
    float mu = 0.f;
#pragma unroll
    for (int o = 0; o < 16; ++o) mu += z[o];
    mu *= (1.f / 16.f);
    float vz = 0.f;
#pragma unroll
    for (int o = 0; o < 16; ++o) { float d2 = z[o] - mu; vz += d2 * d2; }
    vz *= (1.f / 16.f);
    float rs = rsqrtf(vz + 1e-5f);
#pragma unroll
    for (int o = 0; o < 16; ++o)
      z[o] = tanhf((z[o] - mu) * rs * lng[o] + lnb[o]);
    float z2[8];
#pragma unroll
    for (int o = 0; o < 8; ++o) {
      float a = s2b[o];
#pragma unroll
      for (int i = 0; i < 16; ++i) a += s2w[o * 16 + i] * z[i];
      z2[o] = fmaxf(a, 0.f);
    }
#pragma unroll
    for (int q = 0; q < 2; ++q) {
      int o = q * 2;  // controls[0], controls[2]
      float a = ab[o];
#pragma unroll
      for (int i = 0; i < 8; ++i) a += aw[o * 8 + i] * z2[i];
      float cc = 1.f / (1.f + expf(-a));
      if (q == 0) c0s += cc; else c2s += cc;
    }
    g_out[n0 + r] = 1.f / (1.f + expf(-(stat[r] + gb[0])));
  }
#pragma unroll
  for (int d = 1; d < 64; d <<= 1) {
    c0s += __shfl_xor(c0s, d);
    c2s += __shfl_xor(c2s, d);
  }
  if (lane == 0) {
    atomicAdd(&scal[1], c0s);
    atomicAdd(&scal[2], c2s);
  }
}

// ---------------------------------------------------------------- k_hebb
// At its traffic roofline (~110us for ~737MB) — unchanged from r12.
__global__ __launch_bounds__(512, 2) void k_hebb(
    const float* __restrict__ x, const short* __restrict__ v_in,
    const float* __restrict__ g_sig, const float* __restrict__ scal,
    float* __restrict__ colv2, float* __restrict__ parts,
    float* __restrict__ out0) {
  __shared__ __align__(16) unsigned int ldsT[2 * 256 * 17];  // 34 KiB
  unsigned int* vT = ldsT;
  unsigned int* xT = ldsT + 256 * 17;
  int tid = threadIdx.x;
  int lane = tid & 63, wid = tid >> 6;
  int lr = lane & 15, lg = lane >> 4;
  int wr = wid >> 2, wc = wid & 3;
  size_t n0 = (size_t)blockIdx.x * 1024;
  float gv = scal[2] * (1.f / 262144.f);  // gate_value

  f32x4 acc[8][4] = {};
  float cv2[8] = {0.f, 0.f, 0.f, 0.f, 0.f, 0.f, 0.f, 0.f};
  int np = tid >> 5, ic = tid & 31, i0 = ic * 8;

  for (int nt = 0; nt < 32; ++nt) {
    size_t nr = n0 + nt * 32 + np * 2;
    s16x8 va = *(const s16x8*)(v_in + nr * 256 + i0);
    s16x8 vb = *(const s16x8*)(v_in + (nr + 1) * 256 + i0);
    f32x4 xa0 = *(const f32x4*)(x + nr * 256 + i0);
    f32x4 xa1 = *(const f32x4*)(x + nr * 256 + i0 + 4);
    f32x4 xb0 = *(const f32x4*)(x + (nr + 1) * 256 + i0);
    f32x4 xb1 = *(const f32x4*)(x + (nr + 1) * 256 + i0 + 4);
    float sa = g_sig[nr] * gv, sb = g_sig[nr + 1] * gv;
    f32x4 oa0, oa1, ob0, ob1;
#pragma unroll
    for (int j = 0; j < 4; ++j) {
      float fa = b2f(va[j]), fA = b2f(va[4 + j]);
      float fb = b2f(vb[j]), fB = b2f(vb[4 + j]);
      cv2[j] += fa * fa + fb * fb;
      cv2[4 + j] += fA * fA + fB * fB;
      oa0[j] = clip2(fa * sa); oa1[j] = clip2(fA * sa);
      ob0[j] = clip2(fb * sb); ob1[j] = clip2(fB * sb);
      vT[(i0 + j) * 17 + np] = packu(va[j], vb[j]);
      vT[(i0 + 4 + j) * 17 + np] = packu(va[4 + j], vb[4 + j]);
      xT[(i0 + j) * 17 + np] = packu(f2b(xa0[j]), f2b(xb0[j]));
      xT[(i0 + 4 + j) * 17 + np] = packu(f2b(xa1[j]), f2b(xb1[j]));
    }
    *(f32x4*)(out0 + nr * 256 + i0) = oa0;
    *(f32x4*)(out0 + nr * 256 + i0 + 4) = oa1;
    *(f32x4*)(out0 + (nr + 1) * 256 + i0) = ob0;
    *(f32x4*)(out0 + (nr + 1) * 256 + i0 + 4) = ob1;
    __syncthreads();
    int npb = lg * 4;
    s16x8 bfr[4];
#pragma unroll
    for (int nf = 0; nf < 4; ++nf) {
      int j = wc * 64 + nf * 16 + lr;
      u32x4 q;
      q[0] = xT[j * 17 + npb]; q[1] = xT[j * 17 + npb + 1];
      q[2] = xT[j * 17 + npb + 2]; q[3] = xT[j * 17 + npb + 3];
      bfr[nf] = __builtin_bit_cast(s16x8, q);
    }
#pragma unroll
    for (int mf = 0; mf < 8; ++mf) {
      int i = wr * 128 + mf * 16 + lr;
      u32x4 q;
      q[0] = vT[i * 17 + npb]; q[1] = vT[i * 17 + npb + 1];
      q[2] = vT[i * 17 + npb + 2]; q[3] = vT[i * 17 + npb + 3];
      s16x8 afr = __builtin_bit_cast(s16x8, q);
#pragma unroll
      for (int nf = 0; nf < 4; ++nf)
        acc[mf][nf] = mfma16(afr, bfr[nf], acc[mf][nf]);
    }
    __syncthreads();
  }
  // fragment-ordered parts: each thread's f32x4 contiguous (coalesced 16B)
  float* myp = parts + (size_t)blockIdx.x * 65536;
#pragma unroll
  for (int mf = 0; mf < 8; ++mf)
#pragma unroll
    for (int nf = 0; nf < 4; ++nf)
      *(f32x4*)(myp + (size_t)(((wid * 8 + mf) * 4 + nf) * 64 + lane) * 4) =
          acc[mf][nf];
  __syncthreads();
  float* cred = (float*)ldsT;
  if (tid < 256) cred[tid] = 0.f;
  __syncthreads();
#pragma unroll
  for (int j = 0; j < 8; ++j) atomicAdd(&cred[i0 + j], cv2[j]);
  __syncthreads();
  if (tid < 256) atomicAdd(&colv2[tid], cred[tid]);
}

// ---------------------------------------------------------------- k_mem1
__global__ __launch_bounds__(256) void k_mem1(
    const float* __restrict__ parts, const float* __restrict__ colv2,
    const float* __restrict__ sm, float* __restrict__ mem,
    float* __restrict__ scal) {
  int q = blockIdx.x * 256 + threadIdx.x;  // 0..16383
  const float* src = parts + (size_t)q * 4;
  f32x4 acc = {0.f, 0.f, 0.f, 0.f};
#pragma unroll 4
  for (int p = 0; p < 256; ++p) acc += *(const f32x4*)(src + (size_t)p * 65536);
  int lane2 = q & 63, r = q >> 6;
  int lg = lane2 >> 4, lr = lane2 & 15;
  int nf = r & 3, mf = (r >> 2) & 7, wid = r >> 5;
  int wr = wid >> 2, wc = wid & 3;
  int j = wc * 64 + nf * 16 + lr;
  float mr = scal[1] * (1.f / 262144.f);  // metabolic_rate
  float s = 0.f;
#pragma unroll
  for (int e = 0; e < 4; ++e) {
    int i = wr * 128 + mf * 16 + lg * 4 + e;
    float hebb = acc[e] * (1.f / 262144.f);
    float smv = sm[i * 256 + j];
    float forget = colv2[i] * (1.f / 262144.f) * smv;
    float m = smv + tanhf(hebb - forget) * mr * 0.1f;
    mem[i * 256 + j] = m;
    s += m * m;
  }
#pragma unroll
  for (int d = 1; d < 64; d <<= 1) s += __shfl_xor(s, d);
  __shared__ float r4[4];
  if ((threadIdx.x & 63) == 0) r4[threadIdx.x >> 6] = s;
  __syncthreads();
  if (threadIdx.x == 0) atomicAdd(&scal[3], r4[0] + r4[1] + r4[2] + r4[3]);
}

__global__ __launch_bounds__(256) void k_mem2(const float* __restrict__ mem,
                                              const float* __restrict__ scal,
                                              float* __restrict__ out1) {
  int idx = blockIdx.x * 256 + threadIdx.x;
  float scale = 0.5f / fmaxf(sqrtf(scal[3]), 1e-6f);
  out1[idx] = mem[idx] * scale;
}

// ---------------------------------------------------------------- launch
extern "C" void kernel_launch(void* const* d_in, const int* in_sizes, int n_in,
                              void* d_out, int out_size, void* d_ws, size_t ws_size,
                              hipStream_t stream) {
  (void)in_sizes; (void)n_in; (void)out_size; (void)ws_size;
  const float* x   = (const float*)d_in[0];
  const float* Wm  = (const float*)d_in[1];
  const float* Vm  = (const float*)d_in[2];
  const float* gw  = (const float*)d_in[3];
  const float* gb  = (const float*)d_in[4];
  const float* s1w = (const float*)d_in[5];
  const float* s1b = (const float*)d_in[6];
  const float* lng = (const float*)d_in[7];
  const float* lnb = (const float*)d_in[8];
  const float* s2w = (const float*)d_in[9];
  const float* s2b = (const float*)d_in[10];
  const float* aw  = (const float*)d_in[11];
  const float* ab  = (const float*)d_in[12];
  const float* sm  = (const float*)d_in[13];
  float* out0 = (float*)d_out;
  float* out1 = out0 + (size_t)NTOK * 256;

  char* w = (char*)d_ws;
  short* v_ws  = (short*)w;                    // 134217728
  float* g_ws  = (float*)(w + 134217728);      // 1048576
  float* scal  = (float*)(w + 135266304);      // 256
  float* colv2 = (float*)(w + 135266560);      // 1024
  float* mem   = (float*)(w + 135267584);      // 262144
  float* parts = (float*)(w + 135529728);      // 67108864
  short* Vf    = (short*)(w + 202638592);      // 131072 (frag-packed)
  short* Wf    = (short*)(w + 202769664);      // 131072 (frag-packed)

  hipMemsetAsync(scal, 0, 1280, stream);       // scal[64] + colv2[256]
  k_prep<<<16, 1024, 0, stream>>>(Vm, Wm, Vf, Wf, scal);
  k_main<<<256, 512, 0, stream>>>(x, Vf, Wf, gw, gb, s1w, s1b, lng, lnb,
                                  s2w, s2b, aw, ab, v_ws, g_ws, scal);
  k_hebb<<<256, 512, 0, stream>>>(x, v_ws, g_ws, scal, colv2, parts, out0);
  k_mem1<<<64, 256, 0, stream>>>(parts, colv2, sm, mem, scal);
  k_mem2<<<256, 256, 0, stream>>>(mem, scal, out1);
}

// Round 15
// 363.845 us; speedup vs baseline: 1.1518x; 1.0189x over previous
//
#include <hip/hip_runtime.h>
#include <hip/hip_bf16.h>

// MicroContinuumCell — MI355X. f32 I/O; bf16 MFMA internally.
// v15 = r14 + B fragments hoisted to registers (BV/BW[2][8], 128 VGPRs):
// inner loop is pure ds_read+MFMA; no per-subtile L2 B-traffic (was 256KB
// per block-subtile = 2.1GB total). LDS-bound at 1 block/CU so the extra
// registers are free. launch_bounds(512,2) caps 256 VGPR/wave.
// Workspace (~203 MB): offsets in kernel_launch.

#define NTOK 262144

typedef short s16x4 __attribute__((ext_vector_type(4)));
typedef short s16x8 __attribute__((ext_vector_type(8)));
typedef float f32x4 __attribute__((ext_vector_type(4)));
typedef unsigned int u32x4 __attribute__((ext_vector_type(4)));
typedef __bf16 bf16x8 __attribute__((ext_vector_type(8)));

static __device__ __forceinline__ float b2f(short s) {
  unsigned int u = ((unsigned int)(unsigned short)s) << 16;
  return __builtin_bit_cast(float, u);
}
static __device__ __forceinline__ short f2b(float f) {
  __hip_bfloat16 h = __float2bfloat16(f);
  return (short)__builtin_bit_cast(unsigned short, h);
}
static __device__ __forceinline__ float clip2(float f) {
  return fminf(2.f, fmaxf(-2.f, f));
}
static __device__ __forceinline__ unsigned int packu(short lo, short hi) {
  return (unsigned int)(unsigned short)lo | ((unsigned int)(unsigned short)hi << 16);
}
static __device__ __forceinline__ f32x4 mfma16(s16x8 a, s16x8 b, f32x4 c) {
  return __builtin_amdgcn_mfma_f32_16x16x32_bf16(
      __builtin_bit_cast(bf16x8, a), __builtin_bit_cast(bf16x8, b), c, 0, 0, 0);
}

// ---------------------------------------------------------------- k_prep
// Fragment-packs V,W into Vf,Wf (wave B-frag load = 1KB contiguous) + |W|^2.
__global__ __launch_bounds__(1024) void k_prep(const float* __restrict__ V,
                                               const float* __restrict__ W,
                                               short* __restrict__ Vf,
                                               short* __restrict__ Wf,
                                               float* __restrict__ scal) {
  int t = blockIdx.x * 1024 + threadIdx.x;  // 16384 threads x 4 elems
  int flat = t * 4;
  int col = flat >> 8, k0 = flat & 255;
  f32x4 v4 = *(const f32x4*)(V + flat);
  f32x4 w4 = *(const f32x4*)(W + flat);
  s16x4 vb, wb;
  float s = 0.f;
#pragma unroll
  for (int e = 0; e < 4; ++e) {
    vb[e] = f2b(v4[e]);
    wb[e] = f2b(w4[e]);
    s += w4[e] * w4[e];
  }
  int cb = col >> 4, lrr = col & 15;
  int ks = k0 >> 5, lgg = (k0 >> 3) & 3, j0 = k0 & 7;
  size_t g = (size_t)(((cb * 8 + ks) * 4 + lgg) * 16 + lrr) * 8 + j0;
  *(s16x4*)(Vf + g) = vb;
  *(s16x4*)(Wf + g) = wb;
#pragma unroll
  for (int d = 1; d < 64; d <<= 1) s += __shfl_xor(s, d);
  __shared__ float r[16];
  if ((threadIdx.x & 63) == 0) r[threadIdx.x >> 6] = s;
  __syncthreads();
  if (threadIdx.x == 0) {
    float tt = 0.f;
#pragma unroll
    for (int i = 0; i < 16; ++i) tt += r[i];
    atomicAdd(&scal[0], tt);
  }
}

// ---------------------------------------------------------------- k_main
// 256 blocks x 512 threads; 1024 rows/block; 32 subtiles of 32 rows.
// B fragments live in registers for the whole kernel. Single-barrier
// pipelined subtile loop (xs/vs double-buffered).
__global__ __launch_bounds__(512, 2) void k_main(
    const float* __restrict__ x, const short* __restrict__ Vf,
    const short* __restrict__ Wf, const float* __restrict__ gw,
    const float* __restrict__ gb, const float* __restrict__ s1w,
    const float* __restrict__ s1b, const float* __restrict__ lng,
    const float* __restrict__ lnb, const float* __restrict__ s2w,
    const float* __restrict__ s2b, const float* __restrict__ aw,
    const float* __restrict__ ab, short* __restrict__ v_out,
    float* __restrict__ g_out, float* __restrict__ scal) {
  __shared__ __align__(16) short xs[2][8192];      // 2 x 16 KiB frag-ordered
  __shared__ __align__(16) short vs[2][32 * 264];  // 2 x 16.5 KiB v bounce
  __shared__ float stat[4096];  // [0)gate [1024)|h| [2048)sx [3072)sxx
  int tid = threadIdx.x;
  int lane = tid & 63, wid = tid >> 6;
  int lr = lane & 15, lg = lane >> 4;
  int np = tid >> 5, ic = tid & 31;  // staging: rows 2np,2np+1; cols ic*8
  int c0 = wid * 32;                 // wave's 32-col slice (both products)
  size_t n0 = (size_t)blockIdx.x * 1024;

#pragma unroll
  for (int q = 0; q < 4; ++q) stat[q * 512 + tid] = 0.f;

  float gw0 = gw[c0 + lr], gw1 = gw[c0 + 16 + lr];
  int sks = ic >> 2, slg = ic & 3;
  int rowa = 2 * np, rowb = 2 * np + 1;
  int sa = ((rowa >> 4) * 8 + sks) * 64 + ((slg * 16 + (rowa & 15)) ^ sks);
  int sb = ((rowb >> 4) * 8 + sks) * 64 + ((slg * 16 + (rowb & 15)) ^ sks);

  // ---- hoist B fragments into registers (row-invariant; 128 VGPRs)
  s16x8 BV[2][8], BW[2][8];
#pragma unroll
  for (int cb = 0; cb < 2; ++cb)
#pragma unroll
    for (int ks = 0; ks < 8; ++ks) {
      size_t off = (size_t)(((wid * 2 + cb) * 8 + ks) * 64 + lane) * 8;
      BV[cb][ks] = *(const s16x8*)(Vf + off);
      BW[cb][ks] = *(const s16x8*)(Wf + off);
    }

  f32x4 rxa0, rxa1, rxb0, rxb1;  // staged x registers

#define XLOAD(RB)                                              \
  {                                                            \
    const float* pa = x + (n0 + (RB) + rowa) * 256 + ic * 8;   \
    rxa0 = *(const f32x4*)pa;                                  \
    rxa1 = *(const f32x4*)(pa + 4);                            \
    rxb0 = *(const f32x4*)(pa + 256);                          \
    rxb1 = *(const f32x4*)(pa + 260);                          \
  }
#define CONV_STORE(BUF, RB)                                    \
  {                                                            \
    s16x8 ca, cb;                                              \
    float sA = 0.f, qA = 0.f, sB = 0.f, qB = 0.f;              \
    _Pragma("unroll") for (int j = 0; j < 4; ++j) {            \
      sA += rxa0[j] + rxa1[j];                                 \
      qA += rxa0[j] * rxa0[j] + rxa1[j] * rxa1[j];             \
      sB += rxb0[j] + rxb1[j];                                 \
      qB += rxb0[j] * rxb0[j] + rxb1[j] * rxb1[j];             \
      ca[j] = f2b(rxa0[j]); ca[4 + j] = f2b(rxa1[j]);          \
      cb[j] = f2b(rxb0[j]); cb[4 + j] = f2b(rxb1[j]);          \
    }                                                          \
    *(s16x8*)(xs[BUF] + sa * 8) = ca;                          \
    *(s16x8*)(xs[BUF] + sb * 8) = cb;                          \
    _Pragma("unroll") for (int d = 1; d < 32; d <<= 1) {       \
      sA += __shfl_xor(sA, d); qA += __shfl_xor(qA, d);        \
      sB += __shfl_xor(sB, d); qB += __shfl_xor(qB, d);        \
    }                                                          \
    if (ic == 0) {                                             \
      stat[2048 + (RB) + rowa] = sA;                           \
      stat[3072 + (RB) + rowa] = qA;                           \
      stat[2048 + (RB) + rowb] = sB;                           \
      stat[3072 + (RB) + rowb] = qB;                           \
    }                                                          \
  }

  // prologue: stage subtile 0
  XLOAD(0);
  CONV_STORE(0, 0);
  __syncthreads();

  for (int nt = 0; nt < 32; ++nt) {
    int buf = nt & 1;
    int rbase = nt * 32;
    // ---- copy previous subtile's v out (from vs[buf^1])
    if (nt > 0) {
      const short* vsp = vs[buf ^ 1];
#pragma unroll
      for (int q = 0; q < 2; ++q) {
        int item = q * 512 + tid;
        int row = item >> 5, c8 = item & 31;
        *(s16x8*)(v_out + (n0 + rbase - 32 + row) * 256 + c8 * 8) =
            *(const s16x8*)(vsp + row * 264 + c8 * 8);
      }
    }
    // ---- issue next subtile's x loads (consumed AFTER the MFMAs)
    if (nt < 31) XLOAD(rbase + 32);
    // ---- compute: 64 MFMAs from xs[buf] with register-resident B
    f32x4 av[2][2] = {}, ah[2][2] = {};
    const short* xb = xs[buf];
#pragma unroll
    for (int ks = 0; ks < 8; ++ks) {
      s16x8 a0 = *(const s16x8*)(xb + ((ks * 64) + (lane ^ ks)) * 8);
      s16x8 a1 = *(const s16x8*)(xb + (((8 + ks) * 64) + (lane ^ ks)) * 8);
      av[0][0] = mfma16(a0, BV[0][ks], av[0][0]);
      av[0][1] = mfma16(a0, BV[1][ks], av[0][1]);
      av[1][0] = mfma16(a1, BV[0][ks], av[1][0]);
      av[1][1] = mfma16(a1, BV[1][ks], av[1][1]);
      ah[0][0] = mfma16(a0, BW[0][ks], ah[0][0]);
      ah[0][1] = mfma16(a0, BW[1][ks], ah[0][1]);
      ah[1][0] = mfma16(a1, BW[0][ks], ah[1][0]);
      ah[1][1] = mfma16(a1, BW[1][ks], ah[1][1]);
    }
    // clip v, gate-dot & |h| row-partials, v -> vs[buf]
#pragma unroll
    for (int mf = 0; mf < 2; ++mf)
#pragma unroll
      for (int e = 0; e < 4; ++e) {
        float v0 = clip2(av[mf][0][e]), v1 = clip2(av[mf][1][e]);
        av[mf][0][e] = v0; av[mf][1][e] = v1;
        float gd = v0 * gw0 + v1 * gw1;
        float hs = fabsf(ah[mf][0][e]) + fabsf(ah[mf][1][e]);
#pragma unroll
        for (int d = 1; d < 16; d <<= 1) {
          gd += __shfl_xor(gd, d);
          hs += __shfl_xor(hs, d);
        }
        if (lr == 0) {
          int row = rbase + mf * 16 + lg * 4 + e;
          atomicAdd(&stat[row], gd);
          atomicAdd(&stat[1024 + row], hs);
        }
      }
    {
      short* vsc = vs[buf];
#pragma unroll
      for (int mf = 0; mf < 2; ++mf)
#pragma unroll
        for (int nf = 0; nf < 2; ++nf)
#pragma unroll
          for (int e = 0; e < 4; ++e)
            vsc[(mf * 16 + lg * 4 + e) * 264 + c0 + nf * 16 + lr] =
                f2b(av[mf][nf][e]);
    }
    // ---- convert prefetched x -> xs[buf^1] (loads are ~3000cy old now)
    if (nt < 31) CONV_STORE(buf ^ 1, rbase + 32);
    __syncthreads();
  }
  // final subtile's v copy-out (vs[31&1] = vs[1])
  {
    const short* vsp = vs[1];
#pragma unroll
    for (int q = 0; q < 2; ++q) {
      int item = q * 512 + tid;
      int row = item >> 5, c8 = item & 31;
      *(s16x8*)(v_out + (n0 + 992 + row) * 256 + c8 * 8) =
          *(const s16x8*)(vsp + row * 264 + c8 * 8);
    }
  }
#undef CONV_STORE
#undef XLOAD

  // ---- deferred per-row MLP: 2 rows/thread
  float c0s = 0.f, c2s = 0.f;
  float wnorm = sqrtf(scal[0]);
#pragma unroll
  for (int rr = 0; rr < 2; ++rr) {
    int r = tid + rr * 512;
    float mean = stat[2048 + r] * (1.f / 256.f);
    float var = stat[3072 + r] * (1.f / 256.f) - mean * mean;
    float st[4];
    st[0] = fabsf(var - 0.5f);
    st[1] = stat[1024 + r] * (1.f / 256.f);
    st[2] = wnorm;
    st[3] = 0.5f;
    float z[16];
#pragma unroll
    for (int o = 0; o < 16; ++o) {
      float a = s1b[o];
#pragma unroll
      for (int i = 0; i < 4; ++i) a += s1w[o * 4 + i] * st[i];
      z[o] = a;
    }
    float mu = 0.f;
#pragma unroll
    for (int o = 0; o < 16; ++o) mu += z[o];
    mu *= (1.f / 16.f);
    float vz = 0.f;
#pragma unroll
    for (int o = 0; o < 16; ++o) { float d2 = z[o] - mu; vz += d2 * d2; }
    vz *= (1.f / 16.f);
    float rs = rsqrtf(vz + 1e-5f);
#pragma unroll
    for (int o = 0; o < 16; ++o)
      z[o] = tanhf((z[o] - mu) * rs * lng[o] + lnb[o]);
    float z2[8];
#pragma unroll
    for (int o = 0; o < 8; ++o) {
      float a = s2b[o];
#pragma unroll
      for (int i = 0; i < 16; ++i) a += s2w[o * 16 + i] * z[i];
      z2[o] = fmaxf(a, 0.f);
    }
#pragma unroll
    for (int q = 0; q < 2; ++q) {
      int o = q * 2;  // controls[0], controls[2]
      float a = ab[o];
#pragma unroll
      for (int i = 0; i < 8; ++i) a += aw[o * 8 + i] * z2[i];
      float cc = 1.f / (1.f + expf(-a));
      if (q == 0) c0s += cc; else c2s += cc;
    }
    g_out[n0 + r] = 1.f / (1.f + expf(-(stat[r] + gb[0])));
  }
#pragma unroll
  for (int d = 1; d < 64; d <<= 1) {
    c0s += __shfl_xor(c0s, d);
    c2s += __shfl_xor(c2s, d);
  }
  if (lane == 0) {
    atomicAdd(&scal[1], c0s);
    atomicAdd(&scal[2], c2s);
  }
}

// ---------------------------------------------------------------- k_hebb
// At its traffic roofline (~110us for ~737MB) — unchanged from r12.
__global__ __launch_bounds__(512, 2) void k_hebb(
    const float* __restrict__ x, const short* __restrict__ v_in,
    const float* __restrict__ g_sig, const float* __restrict__ scal,
    float* __restrict__ colv2, float* __restrict__ parts,
    float* __restrict__ out0) {
  __shared__ __align__(16) unsigned int ldsT[2 * 256 * 17];  // 34 KiB
  unsigned int* vT = ldsT;
  unsigned int* xT = ldsT + 256 * 17;
  int tid = threadIdx.x;
  int lane = tid & 63, wid = tid >> 6;
  int lr = lane & 15, lg = lane >> 4;
  int wr = wid >> 2, wc = wid & 3;
  size_t n0 = (size_t)blockIdx.x * 1024;
  float gv = scal[2] * (1.f / 262144.f);  // gate_value

  f32x4 acc[8][4] = {};
  float cv2[8] = {0.f, 0.f, 0.f, 0.f, 0.f, 0.f, 0.f, 0.f};
  int np = tid >> 5, ic = tid & 31, i0 = ic * 8;

  for (int nt = 0; nt < 32; ++nt) {
    size_t nr = n0 + nt * 32 + np * 2;
    s16x8 va = *(const s16x8*)(v_in + nr * 256 + i0);
    s16x8 vb = *(const s16x8*)(v_in + (nr + 1) * 256 + i0);
    f32x4 xa0 = *(const f32x4*)(x + nr * 256 + i0);
    f32x4 xa1 = *(const f32x4*)(x + nr * 256 + i0 + 4);
    f32x4 xb0 = *(const f32x4*)(x + (nr + 1) * 256 + i0);
    f32x4 xb1 = *(const f32x4*)(x + (nr + 1) * 256 + i0 + 4);
    float sa = g_sig[nr] * gv, sb = g_sig[nr + 1] * gv;
    f32x4 oa0, oa1, ob0, ob1;
#pragma unroll
    for (int j = 0; j < 4; ++j) {
      float fa = b2f(va[j]), fA = b2f(va[4 + j]);
      float fb = b2f(vb[j]), fB = b2f(vb[4 + j]);
      cv2[j] += fa * fa + fb * fb;
      cv2[4 + j] += fA * fA + fB * fB;
      oa0[j] = clip2(fa * sa); oa1[j] = clip2(fA * sa);
      ob0[j] = clip2(fb * sb); ob1[j] = clip2(fB * sb);
      vT[(i0 + j) * 17 + np] = packu(va[j], vb[j]);
      vT[(i0 + 4 + j) * 17 + np] = packu(va[4 + j], vb[4 + j]);
      xT[(i0 + j) * 17 + np] = packu(f2b(xa0[j]), f2b(xb0[j]));
      xT[(i0 + 4 + j) * 17 + np] = packu(f2b(xa1[j]), f2b(xb1[j]));
    }
    *(f32x4*)(out0 + nr * 256 + i0) = oa0;
    *(f32x4*)(out0 + nr * 256 + i0 + 4) = oa1;
    *(f32x4*)(out0 + (nr + 1) * 256 + i0) = ob0;
    *(f32x4*)(out0 + (nr + 1) * 256 + i0 + 4) = ob1;
    __syncthreads();
    int npb = lg * 4;
    s16x8 bfr[4];
#pragma unroll
    for (int nf = 0; nf < 4; ++nf) {
      int j = wc * 64 + nf * 16 + lr;
      u32x4 q;
      q[0] = xT[j * 17 + npb]; q[1] = xT[j * 17 + npb + 1];
      q[2] = xT[j * 17 + npb + 2]; q[3] = xT[j * 17 + npb + 3];
      bfr[nf] = __builtin_bit_cast(s16x8, q);
    }
#pragma unroll
    for (int mf = 0; mf < 8; ++mf) {
      int i = wr * 128 + mf * 16 + lr;
      u32x4 q;
      q[0] = vT[i * 17 + npb]; q[1] = vT[i * 17 + npb + 1];
      q[2] = vT[i * 17 + npb + 2]; q[3] = vT[i * 17 + npb + 3];
      s16x8 afr = __builtin_bit_cast(s16x8, q);
#pragma unroll
      for (int nf = 0; nf < 4; ++nf)
        acc[mf][nf] = mfma16(afr, bfr[nf], acc[mf][nf]);
    }
    __syncthreads();
  }
  // fragment-ordered parts: each thread's f32x4 contiguous (coalesced 16B)
  float* myp = parts + (size_t)blockIdx.x * 65536;
#pragma unroll
  for (int mf = 0; mf < 8; ++mf)
#pragma unroll
    for (int nf = 0; nf < 4; ++nf)
      *(f32x4*)(myp + (size_t)(((wid * 8 + mf) * 4 + nf) * 64 + lane) * 4) =
          acc[mf][nf];
  __syncthreads();
  float* cred = (float*)ldsT;
  if (tid < 256) cred[tid] = 0.f;
  __syncthreads();
#pragma unroll
  for (int j = 0; j < 8; ++j) atomicAdd(&cred[i0 + j], cv2[j]);
  __syncthreads();
  if (tid < 256) atomicAdd(&colv2[tid], cred[tid]);
}

// ---------------------------------------------------------------- k_mem1
__global__ __launch_bounds__(256) void k_mem1(
    const float* __restrict__ parts, const float* __restrict__ colv2,
    const float* __restrict__ sm, float* __restrict__ mem,
    float* __restrict__ scal) {
  int q = blockIdx.x * 256 + threadIdx.x;  // 0..16383
  const float* src = parts + (size_t)q * 4;
  f32x4 acc = {0.f, 0.f, 0.f, 0.f};
#pragma unroll 4
  for (int p = 0; p < 256; ++p) acc += *(const f32x4*)(src + (size_t)p * 65536);
  int lane2 = q & 63, r = q >> 6;
  int lg = lane2 >> 4, lr = lane2 & 15;
  int nf = r & 3, mf = (r >> 2) & 7, wid = r >> 5;
  int wr = wid >> 2, wc = wid & 3;
  int j = wc * 64 + nf * 16 + lr;
  float mr = scal[1] * (1.f / 262144.f);  // metabolic_rate
  float s = 0.f;
#pragma unroll
  for (int e = 0; e < 4; ++e) {
    int i = wr * 128 + mf * 16 + lg * 4 + e;
    float hebb = acc[e] * (1.f / 262144.f);
    float smv = sm[i * 256 + j];
    float forget = colv2[i] * (1.f / 262144.f) * smv;
    float m = smv + tanhf(hebb - forget) * mr * 0.1f;
    mem[i * 256 + j] = m;
    s += m * m;
  }
#pragma unroll
  for (int d = 1; d < 64; d <<= 1) s += __shfl_xor(s, d);
  __shared__ float r4[4];
  if ((threadIdx.x & 63) == 0) r4[threadIdx.x >> 6] = s;
  __syncthreads();
  if (threadIdx.x == 0) atomicAdd(&scal[3], r4[0] + r4[1] + r4[2] + r4[3]);
}

__global__ __launch_bounds__(256) void k_mem2(const float* __restrict__ mem,
                                              const float* __restrict__ scal,
                                              float* __restrict__ out1) {
  int idx = blockIdx.x * 256 + threadIdx.x;
  float scale = 0.5f / fmaxf(sqrtf(scal[3]), 1e-6f);
  out1[idx] = mem[idx] * scale;
}

// ---------------------------------------------------------------- launch
extern "C" void kernel_launch(void* const* d_in, const int* in_sizes, int n_in,
                              void* d_out, int out_size, void* d_ws, size_t ws_size,
                              hipStream_t stream) {
  (void)in_sizes; (void)n_in; (void)out_size; (void)ws_size;
  const float* x   = (const float*)d_in[0];
  const float* Wm  = (const float*)d_in[1];
  const float* Vm  = (const float*)d_in[2];
  const float* gw  = (const float*)d_in[3];
  const float* gb  = (const float*)d_in[4];
  const float* s1w = (const float*)d_in[5];
  const float* s1b = (const float*)d_in[6];
  const float* lng = (const float*)d_in[7];
  const float* lnb = (const float*)d_in[8];
  const float* s2w = (const float*)d_in[9];
  const float* s2b = (const float*)d_in[10];
  const float* aw  = (const float*)d_in[11];
  const float* ab  = (const float*)d_in[12];
  const float* sm  = (const float*)d_in[13];
  float* out0 = (float*)d_out;
  float* out1 = out0 + (size_t)NTOK * 256;

  char* w = (char*)d_ws;
  short* v_ws  = (short*)w;                    // 134217728
  float* g_ws  = (float*)(w + 134217728);      // 1048576
  float* scal  = (float*)(w + 135266304);      // 256
  float* colv2 = (float*)(w + 135266560);      // 1024
  float* mem   = (float*)(w + 135267584);      // 262144
  float* parts = (float*)(w + 135529728);      // 67108864
  short* Vf    = (short*)(w + 202638592);      // 131072 (frag-packed)
  short* Wf    = (short*)(w + 202769664);      // 131072 (frag-packed)

  hipMemsetAsync(scal, 0, 1280, stream);       // scal[64] + colv2[256]
  k_prep<<<16, 1024, 0, stream>>>(Vm, Wm, Vf, Wf, scal);
  k_main<<<256, 512, 0, stream>>>(x, Vf, Wf, gw, gb, s1w, s1b, lng, lnb,
                                  s2w, s2b, aw, ab, v_ws, g_ws, scal);
  k_hebb<<<256, 512, 0, stream>>>(x, v_ws, g_ws, scal, colv2, parts, out0);
  k_mem1<<<64, 256, 0, stream>>>(parts, colv2, sm, mem, scal);
  k_mem2<<<256, 256, 0, stream>>>(mem, scal, out1);
}